// Round 2
// baseline (678.255 us; speedup 1.0000x reference)
//
#include <hip/hip_runtime.h>
#include <hip/hip_bf16.h>
#include <math.h>

// Problem constants: B=512, L=128, D=512, H=8, HD=64
// M = B*L = 65536, K = D = 512, N_qkv = 3D = 1536.

typedef __attribute__((ext_vector_type(4))) float f32x4;
typedef __attribute__((ext_vector_type(8))) short bf16x8;
typedef __attribute__((ext_vector_type(4))) short bf16x4;

__device__ __forceinline__ unsigned short f2bf(float f) {
  union { float f; unsigned u; } x; x.f = f;
  return (unsigned short)((x.u + 0x7FFFu + ((x.u >> 16) & 1u)) >> 16);
}

// ---------------- f32 -> bf16 convert (weights) ----------------
__global__ void cvt_f32_bf16(const float* __restrict__ in,
                             unsigned short* __restrict__ out, int n8) {
  int i = blockIdx.x * blockDim.x + threadIdx.x;
  if (i >= n8) return;
  const float4* p = (const float4*)in + (size_t)i * 2;
  float4 a = p[0], b = p[1];
  union { bf16x8 v; short s[8]; } o;
  o.s[0] = (short)f2bf(a.x); o.s[1] = (short)f2bf(a.y);
  o.s[2] = (short)f2bf(a.z); o.s[3] = (short)f2bf(a.w);
  o.s[4] = (short)f2bf(b.x); o.s[5] = (short)f2bf(b.y);
  o.s[6] = (short)f2bf(b.z); o.s[7] = (short)f2bf(b.w);
  *(bf16x8*)(out + (size_t)i * 8) = o.v;
}

// ---------------- GEMM  C = A @ Bt^T  (Bt is N x K row-major) ----------------
// MODE 0: A = f32 (x), convert on the fly; C -> bf16 qkv, (acc+bias)*0.125 for col<512
// MODE 1: A = bf16 (o); C -> f32 h = acc + bias + resid
// tile 128x128, BK=64, 256 threads (4 waves, 2x2 of 64x64), LDS ld=72 (pad).
template <int MODE>
__global__ __launch_bounds__(256, 2) void gemm_bt(
    const float* __restrict__ Af, const unsigned short* __restrict__ Ab,
    const unsigned short* __restrict__ Bt,
    unsigned short* __restrict__ Cb, float* __restrict__ Cf,
    const float* __restrict__ bias, const float* __restrict__ resid, int ldC) {
  constexpr int K = 512;
  __shared__ __align__(16) unsigned short As[128 * 72];
  __shared__ __align__(16) unsigned short Bs[128 * 72];
  const int t = threadIdx.x;
  const int w = t >> 6, lane = t & 63;
  const int wr = w >> 1, wc = w & 1;
  const int g = lane >> 4, l16 = lane & 15;
  const long rowBase = (long)blockIdx.x * 128;
  const long colBase = (long)blockIdx.y * 128;

  f32x4 acc[4][4] = {};

  for (int k0 = 0; k0 < K; k0 += 64) {
    if constexpr (MODE == 0) {
#pragma unroll
      for (int i = 0; i < 8; ++i) {
        int q = t + i * 256;
        int row = q >> 4, c4 = q & 15;
        float4 v = *(const float4*)(Af + (rowBase + row) * 512 + k0 + c4 * 4);
        bf16x4 pk;
        pk[0] = (short)f2bf(v.x); pk[1] = (short)f2bf(v.y);
        pk[2] = (short)f2bf(v.z); pk[3] = (short)f2bf(v.w);
        *(bf16x4*)&As[row * 72 + c4 * 4] = pk;
      }
    } else {
#pragma unroll
      for (int i = 0; i < 4; ++i) {
        int q = t + i * 256;
        int row = q >> 3, c8 = q & 7;
        bf16x8 v = *(const bf16x8*)(Ab + (rowBase + row) * 512 + k0 + c8 * 8);
        *(bf16x8*)&As[row * 72 + c8 * 8] = v;
      }
    }
#pragma unroll
    for (int i = 0; i < 4; ++i) {
      int q = t + i * 256;
      int row = q >> 3, c8 = q & 7;
      bf16x8 v = *(const bf16x8*)(Bt + (colBase + row) * 512 + k0 + c8 * 8);
      *(bf16x8*)&Bs[row * 72 + c8 * 8] = v;
    }
    __syncthreads();
#pragma unroll
    for (int kk = 0; kk < 2; ++kk) {
      bf16x8 af[4], bfr[4];
#pragma unroll
      for (int fm = 0; fm < 4; ++fm)
        af[fm] = *(const bf16x8*)&As[(wr * 64 + fm * 16 + l16) * 72 + kk * 32 + g * 8];
#pragma unroll
      for (int fn = 0; fn < 4; ++fn)
        bfr[fn] = *(const bf16x8*)&Bs[(wc * 64 + fn * 16 + l16) * 72 + kk * 32 + g * 8];
#pragma unroll
      for (int fm = 0; fm < 4; ++fm)
#pragma unroll
        for (int fn = 0; fn < 4; ++fn)
          acc[fm][fn] = __builtin_amdgcn_mfma_f32_16x16x32_bf16(af[fm], bfr[fn], acc[fm][fn], 0, 0, 0);
    }
    __syncthreads();
  }

#pragma unroll
  for (int fm = 0; fm < 4; ++fm) {
#pragma unroll
    for (int fn = 0; fn < 4; ++fn) {
      long col = colBase + wc * 64 + fn * 16 + l16;
      float bcol = bias[col];
#pragma unroll
      for (int r = 0; r < 4; ++r) {
        long row = rowBase + wr * 64 + fm * 16 + g * 4 + r;
        float v = acc[fm][fn][r] + bcol;
        if constexpr (MODE == 0) {
          if (col < 512) v *= 0.125f;  // q * HD^-0.5
          Cb[row * ldC + col] = f2bf(v);
        } else {
          Cf[row * ldC + col] = v + resid[row * ldC + col];
        }
      }
    }
  }
}

// ---------------- attention per (b, h) ----------------
// 256 threads = 4 waves; wave w owns query rows [w*32, w*32+32).
// q,k fragments straight from global; V transposed into LDS; P via wave-private LDS.
__global__ __launch_bounds__(256, 2) void attn_kernel(
    const unsigned short* __restrict__ qkv, const float* __restrict__ corr,
    const int* __restrict__ mask, const float* __restrict__ bias_scale,
    unsigned short* __restrict__ o) {
  __shared__ __align__(16) unsigned short Pl[4][32 * 136];
  __shared__ __align__(16) unsigned short vt[64 * 136];
  __shared__ float biasl[128];
  const int t = threadIdx.x;
  const int w = t >> 6, lane = t & 63;
  const int g = lane >> 4, l16 = lane & 15;
  const int b = blockIdx.x >> 3, h = blockIdx.x & 7;
  const long qkvBase = (long)b * 128 * 1536;

  // stage V^T : vt[d][s] = v[s][d]
#pragma unroll
  for (int i = 0; i < 4; ++i) {
    int q = t + i * 256;
    int row = q >> 3, c8 = q & 7;
    union { bf16x8 v; unsigned short s[8]; } u;
    u.v = *(const bf16x8*)(qkv + qkvBase + (long)row * 1536 + 1024 + h * 64 + c8 * 8);
#pragma unroll
    for (int j = 0; j < 8; ++j) vt[(c8 * 8 + j) * 136 + row] = u.s[j];
  }
  if (t < 128) {
    float bs = bias_scale[0];
    biasl[t] = mask[b * 128 + t] ? -INFINITY : bs * corr[b * 128 + t];
  }

  // q (A-op) and k (B-op) fragments direct from global
  bf16x8 aq[2][2], bk[8][2];
#pragma unroll
  for (int fm = 0; fm < 2; ++fm)
#pragma unroll
    for (int kk = 0; kk < 2; ++kk)
      aq[fm][kk] = *(const bf16x8*)(qkv + qkvBase + (long)(w * 32 + fm * 16 + l16) * 1536 + h * 64 + kk * 32 + g * 8);
#pragma unroll
  for (int fn = 0; fn < 8; ++fn)
#pragma unroll
    for (int kk = 0; kk < 2; ++kk)
      bk[fn][kk] = *(const bf16x8*)(qkv + qkvBase + (long)(fn * 16 + l16) * 1536 + 512 + h * 64 + kk * 32 + g * 8);

  __syncthreads();  // vt + biasl ready

  // S = q @ k^T  (rows l, cols s); D frag: col s = l16, row l = g*4+r
  f32x4 accS[2][8] = {};
#pragma unroll
  for (int kk = 0; kk < 2; ++kk)
#pragma unroll
    for (int fm = 0; fm < 2; ++fm)
#pragma unroll
      for (int fn = 0; fn < 8; ++fn)
        accS[fm][fn] = __builtin_amdgcn_mfma_f32_16x16x32_bf16(aq[fm][kk], bk[fn][kk], accS[fm][fn], 0, 0, 0);

  float bv[8];
#pragma unroll
  for (int fn = 0; fn < 8; ++fn) bv[fn] = biasl[fn * 16 + l16];

  float rinv[2][4];
#pragma unroll
  for (int fm = 0; fm < 2; ++fm) {
#pragma unroll
    for (int r = 0; r < 4; ++r) {
      float m = -INFINITY;
#pragma unroll
      for (int fn = 0; fn < 8; ++fn) m = fmaxf(m, accS[fm][fn][r] + bv[fn]);
#pragma unroll
      for (int off = 1; off < 16; off <<= 1) m = fmaxf(m, __shfl_xor(m, off));
      float s = 0.f;
#pragma unroll
      for (int fn = 0; fn < 8; ++fn) {
        float p = __expf(accS[fm][fn][r] + bv[fn] - m);
        accS[fm][fn][r] = p;
        s += p;
      }
#pragma unroll
      for (int off = 1; off < 16; off <<= 1) s += __shfl_xor(s, off);
      rinv[fm][r] = 1.0f / s;
#pragma unroll
      for (int fn = 0; fn < 8; ++fn)
        Pl[w][(fm * 16 + g * 4 + r) * 136 + fn * 16 + l16] = f2bf(accS[fm][fn][r]);
    }
  }

  // O = P @ V  (wave-private P rows; vt is cross-wave but synced above)
  f32x4 accO[2][4] = {};
#pragma unroll
  for (int kk = 0; kk < 4; ++kk) {
    bf16x8 ap[2], bw[4];
#pragma unroll
    for (int fm = 0; fm < 2; ++fm)
      ap[fm] = *(const bf16x8*)&Pl[w][(fm * 16 + l16) * 136 + kk * 32 + g * 8];
#pragma unroll
    for (int fn = 0; fn < 4; ++fn)
      bw[fn] = *(const bf16x8*)&vt[(fn * 16 + l16) * 136 + kk * 32 + g * 8];
#pragma unroll
    for (int fm = 0; fm < 2; ++fm)
#pragma unroll
      for (int fn = 0; fn < 4; ++fn)
        accO[fm][fn] = __builtin_amdgcn_mfma_f32_16x16x32_bf16(ap[fm], bw[fn], accO[fm][fn], 0, 0, 0);
  }

  const long oBase = (long)b * 128 * 512 + (long)h * 64;
#pragma unroll
  for (int fm = 0; fm < 2; ++fm)
#pragma unroll
    for (int fn = 0; fn < 4; ++fn)
#pragma unroll
      for (int r = 0; r < 4; ++r)
        o[oBase + (long)(w * 32 + fm * 16 + g * 4 + r) * 512 + fn * 16 + l16] =
            f2bf(accO[fm][fn][r] * rinv[fm][r]);
}

// ---------------- in-place LayerNorm over rows of 512 ----------------
__global__ __launch_bounds__(256) void ln_kernel(float* __restrict__ h,
                                                 const float* __restrict__ lnw,
                                                 const float* __restrict__ lnb) {
  const int t = threadIdx.x;
  const int w = t >> 6, lane = t & 63;
  const long row = (long)blockIdx.x * 4 + w;
  float* rp = h + row * 512;
  float4 v0 = *(float4*)(rp + lane * 4);
  float4 v1 = *(float4*)(rp + 256 + lane * 4);
  float s = ((v0.x + v0.y) + (v0.z + v0.w)) + ((v1.x + v1.y) + (v1.z + v1.w));
#pragma unroll
  for (int off = 1; off < 64; off <<= 1) s += __shfl_xor(s, off);
  float mu = s * (1.0f / 512.0f);
  float vs = (v0.x - mu) * (v0.x - mu) + (v0.y - mu) * (v0.y - mu) +
             (v0.z - mu) * (v0.z - mu) + (v0.w - mu) * (v0.w - mu) +
             (v1.x - mu) * (v1.x - mu) + (v1.y - mu) * (v1.y - mu) +
             (v1.z - mu) * (v1.z - mu) + (v1.w - mu) * (v1.w - mu);
#pragma unroll
  for (int off = 1; off < 64; off <<= 1) vs += __shfl_xor(vs, off);
  float rstd = rsqrtf(vs * (1.0f / 512.0f) + 1e-5f);
  float4 w0 = *(const float4*)(lnw + lane * 4);
  float4 w1 = *(const float4*)(lnw + 256 + lane * 4);
  float4 b0 = *(const float4*)(lnb + lane * 4);
  float4 b1 = *(const float4*)(lnb + 256 + lane * 4);
  float4 o0, o1;
  o0.x = (v0.x - mu) * rstd * w0.x + b0.x;
  o0.y = (v0.y - mu) * rstd * w0.y + b0.y;
  o0.z = (v0.z - mu) * rstd * w0.z + b0.z;
  o0.w = (v0.w - mu) * rstd * w0.w + b0.w;
  o1.x = (v1.x - mu) * rstd * w1.x + b1.x;
  o1.y = (v1.y - mu) * rstd * w1.y + b1.y;
  o1.z = (v1.z - mu) * rstd * w1.z + b1.z;
  o1.w = (v1.w - mu) * rstd * w1.w + b1.w;
  *(float4*)(rp + lane * 4) = o0;
  *(float4*)(rp + 256 + lane * 4) = o1;
}

extern "C" void kernel_launch(void* const* d_in, const int* in_sizes, int n_in,
                              void* d_out, int out_size, void* d_ws, size_t ws_size,
                              hipStream_t stream) {
  const float* x = (const float*)d_in[0];
  const float* corr = (const float*)d_in[1];
  const int* mask = (const int*)d_in[2];
  const float* w_in = (const float*)d_in[3];
  const float* b_in = (const float*)d_in[4];
  const float* w_out = (const float*)d_in[5];
  const float* b_out = (const float*)d_in[6];
  const float* ln_w = (const float*)d_in[7];
  const float* ln_b = (const float*)d_in[8];
  const float* bscale = (const float*)d_in[9];

  unsigned short* wqkv_bf = (unsigned short*)d_ws;          // 786432
  unsigned short* wout_bf = wqkv_bf + 786432;               // 262144
  unsigned short* qkv = wout_bf + 262144;                   // 65536*1536
  unsigned short* ob = qkv + (size_t)65536 * 1536;          // 65536*512

  cvt_f32_bf16<<<dim3(384), dim3(256), 0, stream>>>(w_in, wqkv_bf, 98304);
  cvt_f32_bf16<<<dim3(128), dim3(256), 0, stream>>>(w_out, wout_bf, 32768);

  gemm_bt<0><<<dim3(512, 12), dim3(256), 0, stream>>>(
      x, (const unsigned short*)nullptr, wqkv_bf, qkv, (float*)nullptr,
      b_in, (const float*)nullptr, 1536);

  attn_kernel<<<dim3(4096), dim3(256), 0, stream>>>(qkv, corr, mask, bscale, ob);

  gemm_bt<1><<<dim3(512, 4), dim3(256), 0, stream>>>(
      (const float*)nullptr, ob, wout_bf, (unsigned short*)nullptr, (float*)d_out,
      b_out, x, 512);

  ln_kernel<<<dim3(16384), dim3(256), 0, stream>>>((float*)d_out, ln_w, ln_b);
}

// Round 3
// 608.568 us; speedup vs baseline: 1.1145x; 1.1145x over previous
//
#include <hip/hip_runtime.h>
#include <hip/hip_bf16.h>
#include <math.h>

// Problem constants: B=512, L=128, D=512, H=8, HD=64
// M = B*L = 65536, K = D = 512, N_qkv = 3D = 1536.

typedef __attribute__((ext_vector_type(4))) float f32x4;
typedef __attribute__((ext_vector_type(8))) short bf16x8;

__device__ __forceinline__ unsigned short f2bf(float f) {
  union { float f; unsigned u; } x; x.f = f;
  return (unsigned short)((x.u + 0x7FFFu + ((x.u >> 16) & 1u)) >> 16);
}

__device__ __forceinline__ void gload16(const void* g, void* l) {
  __builtin_amdgcn_global_load_lds((const __attribute__((address_space(1))) void*)g,
                                   (__attribute__((address_space(3))) void*)l, 16, 0, 0);
}

// ---------------- f32 -> bf16 convert ----------------
__global__ void cvt_f32_bf16(const float* __restrict__ in,
                             unsigned short* __restrict__ out, int n8) {
  int i = blockIdx.x * blockDim.x + threadIdx.x;
  if (i >= n8) return;
  const float4* p = (const float4*)in + (size_t)i * 2;
  float4 a = p[0], b = p[1];
  union { bf16x8 v; short s[8]; } o;
  o.s[0] = (short)f2bf(a.x); o.s[1] = (short)f2bf(a.y);
  o.s[2] = (short)f2bf(a.z); o.s[3] = (short)f2bf(a.w);
  o.s[4] = (short)f2bf(b.x); o.s[5] = (short)f2bf(b.y);
  o.s[6] = (short)f2bf(b.z); o.s[7] = (short)f2bf(b.w);
  *(bf16x8*)(out + (size_t)i * 8) = o.v;
}

// ---------------- GEMM  C = A @ Bt^T  (A: Mx512 bf16, Bt: Nx512 bf16) --------
// m97 structure: 128x128 tile, BK=64, 256 thr (4 waves, 2x2 of 64x64),
// global_load_lds 16B staging, linear LDS [128][64] with T2 XOR swizzle via
// pre-swizzled SOURCE (rule 21: linear dest + inverse-swz source + swz read).
// XCD-aware block swizzle: consecutive nid on one XCD share the A row-block.
// MODE 0: C -> bf16, (acc+bias)*0.125 for col<512 (q scale)
// MODE 1: C -> f32 h = acc + bias + resid
template <int MODE, int NBX>
__global__ __launch_bounds__(256, 3) void gemm_lds(
    const unsigned short* __restrict__ A, const unsigned short* __restrict__ Bt,
    unsigned short* __restrict__ Cb, float* __restrict__ Cf,
    const float* __restrict__ bias, const float* __restrict__ resid, int ldC) {
  __shared__ __align__(16) unsigned short As[128 * 64];
  __shared__ __align__(16) unsigned short Bs[128 * 64];
  const int t = threadIdx.x;
  const int w = t >> 6, lane = t & 63;
  const int wr = w >> 1, wc = w & 1;
  const int g = lane >> 4, l16 = lane & 15;
  const int bid = blockIdx.x;
  const int cpx = (int)(gridDim.x >> 3);          // grid divisible by 8
  const int nid = (bid & 7) * cpx + (bid >> 3);   // bijective XCD swizzle
  const long rowBase = (long)(nid / NBX) * 128;
  const long colBase = (long)(nid % NBX) * 128;

  f32x4 acc[4][4] = {};

  for (int k0 = 0; k0 < 512; k0 += 64) {
#pragma unroll
    for (int i = 0; i < 4; ++i) {
      int flat = i * 256 + t;                      // 16B chunk index
      int row = flat >> 3;
      int c8 = ((flat & 7) ^ (row & 7)) << 3;      // pre-swizzled source chunk
      gload16(A + (rowBase + row) * 512 + k0 + c8, (char*)As + flat * 16);
      gload16(Bt + (colBase + row) * 512 + k0 + c8, (char*)Bs + flat * 16);
    }
    __syncthreads();  // vmcnt(0) drain + barrier
#pragma unroll
    for (int kk = 0; kk < 2; ++kk) {
      bf16x8 af[4], bfr[4];
#pragma unroll
      for (int fm = 0; fm < 4; ++fm) {
        int r = wr * 64 + fm * 16 + l16;
        af[fm] = *(const bf16x8*)((char*)As + r * 128 + ((kk * 64 + g * 16) ^ ((r & 7) << 4)));
      }
#pragma unroll
      for (int fn = 0; fn < 4; ++fn) {
        int r = wc * 64 + fn * 16 + l16;
        bfr[fn] = *(const bf16x8*)((char*)Bs + r * 128 + ((kk * 64 + g * 16) ^ ((r & 7) << 4)));
      }
#pragma unroll
      for (int fm = 0; fm < 4; ++fm)
#pragma unroll
        for (int fn = 0; fn < 4; ++fn)
          acc[fm][fn] = __builtin_amdgcn_mfma_f32_16x16x32_bf16(af[fm], bfr[fn], acc[fm][fn], 0, 0, 0);
    }
    __syncthreads();
  }

#pragma unroll
  for (int fm = 0; fm < 4; ++fm) {
#pragma unroll
    for (int fn = 0; fn < 4; ++fn) {
      long col = colBase + wc * 64 + fn * 16 + l16;
      float bcol = bias[col];
#pragma unroll
      for (int r = 0; r < 4; ++r) {
        long row = rowBase + wr * 64 + fm * 16 + g * 4 + r;
        float v = acc[fm][fn][r] + bcol;
        if constexpr (MODE == 0) {
          if (col < 512) v *= 0.125f;  // q * HD^-0.5
          Cb[row * ldC + col] = f2bf(v);
        } else {
          Cf[row * ldC + col] = v + resid[row * ldC + col];
        }
      }
    }
  }
}

// ---------------- attention per (b, h) ----------------
__global__ __launch_bounds__(256, 2) void attn_kernel(
    const unsigned short* __restrict__ qkv, const float* __restrict__ corr,
    const int* __restrict__ mask, const float* __restrict__ bias_scale,
    unsigned short* __restrict__ o) {
  __shared__ __align__(16) unsigned short Pl[4][32 * 136];
  __shared__ __align__(16) unsigned short vt[64 * 136];
  __shared__ float biasl[128];
  const int t = threadIdx.x;
  const int w = t >> 6, lane = t & 63;
  const int g = lane >> 4, l16 = lane & 15;
  const int b = blockIdx.x >> 3, h = blockIdx.x & 7;
  const long qkvBase = (long)b * 128 * 1536;

  // stage V^T : vt[d][s] = v[s][d]
#pragma unroll
  for (int i = 0; i < 4; ++i) {
    int q = t + i * 256;
    int row = q >> 3, c8 = q & 7;
    union { bf16x8 v; unsigned short s[8]; } u;
    u.v = *(const bf16x8*)(qkv + qkvBase + (long)row * 1536 + 1024 + h * 64 + c8 * 8);
#pragma unroll
    for (int j = 0; j < 8; ++j) vt[(c8 * 8 + j) * 136 + row] = u.s[j];
  }
  if (t < 128) {
    float bs = bias_scale[0];
    biasl[t] = mask[b * 128 + t] ? -INFINITY : bs * corr[b * 128 + t];
  }

  bf16x8 aq[2][2], bk[8][2];
#pragma unroll
  for (int fm = 0; fm < 2; ++fm)
#pragma unroll
    for (int kk = 0; kk < 2; ++kk)
      aq[fm][kk] = *(const bf16x8*)(qkv + qkvBase + (long)(w * 32 + fm * 16 + l16) * 1536 + h * 64 + kk * 32 + g * 8);
#pragma unroll
  for (int fn = 0; fn < 8; ++fn)
#pragma unroll
    for (int kk = 0; kk < 2; ++kk)
      bk[fn][kk] = *(const bf16x8*)(qkv + qkvBase + (long)(fn * 16 + l16) * 1536 + 512 + h * 64 + kk * 32 + g * 8);

  __syncthreads();

  f32x4 accS[2][8] = {};
#pragma unroll
  for (int kk = 0; kk < 2; ++kk)
#pragma unroll
    for (int fm = 0; fm < 2; ++fm)
#pragma unroll
      for (int fn = 0; fn < 8; ++fn)
        accS[fm][fn] = __builtin_amdgcn_mfma_f32_16x16x32_bf16(aq[fm][kk], bk[fn][kk], accS[fm][fn], 0, 0, 0);

  float bv[8];
#pragma unroll
  for (int fn = 0; fn < 8; ++fn) bv[fn] = biasl[fn * 16 + l16];

  float rinv[2][4];
#pragma unroll
  for (int fm = 0; fm < 2; ++fm) {
#pragma unroll
    for (int r = 0; r < 4; ++r) {
      float m = -INFINITY;
#pragma unroll
      for (int fn = 0; fn < 8; ++fn) m = fmaxf(m, accS[fm][fn][r] + bv[fn]);
#pragma unroll
      for (int off = 1; off < 16; off <<= 1) m = fmaxf(m, __shfl_xor(m, off));
      float s = 0.f;
#pragma unroll
      for (int fn = 0; fn < 8; ++fn) {
        float p = __expf(accS[fm][fn][r] + bv[fn] - m);
        accS[fm][fn][r] = p;
        s += p;
      }
#pragma unroll
      for (int off = 1; off < 16; off <<= 1) s += __shfl_xor(s, off);
      rinv[fm][r] = 1.0f / s;
#pragma unroll
      for (int fn = 0; fn < 8; ++fn)
        Pl[w][(fm * 16 + g * 4 + r) * 136 + fn * 16 + l16] = f2bf(accS[fm][fn][r]);
    }
  }

  f32x4 accO[2][4] = {};
#pragma unroll
  for (int kk = 0; kk < 4; ++kk) {
    bf16x8 ap[2], bw[4];
#pragma unroll
    for (int fm = 0; fm < 2; ++fm)
      ap[fm] = *(const bf16x8*)&Pl[w][(fm * 16 + l16) * 136 + kk * 32 + g * 8];
#pragma unroll
    for (int fn = 0; fn < 4; ++fn)
      bw[fn] = *(const bf16x8*)&vt[(fn * 16 + l16) * 136 + kk * 32 + g * 8];
#pragma unroll
    for (int fm = 0; fm < 2; ++fm)
#pragma unroll
      for (int fn = 0; fn < 4; ++fn)
        accO[fm][fn] = __builtin_amdgcn_mfma_f32_16x16x32_bf16(ap[fm], bw[fn], accO[fm][fn], 0, 0, 0);
  }

  const long oBase = (long)b * 128 * 512 + (long)h * 64;
#pragma unroll
  for (int fm = 0; fm < 2; ++fm)
#pragma unroll
    for (int fn = 0; fn < 4; ++fn)
#pragma unroll
      for (int r = 0; r < 4; ++r)
        o[oBase + (long)(w * 32 + fm * 16 + g * 4 + r) * 512 + fn * 16 + l16] =
            f2bf(accO[fm][fn][r] * rinv[fm][r]);
}

// ---------------- in-place LayerNorm over rows of 512 ----------------
__global__ __launch_bounds__(256) void ln_kernel(float* __restrict__ h,
                                                 const float* __restrict__ lnw,
                                                 const float* __restrict__ lnb) {
  const int t = threadIdx.x;
  const int w = t >> 6, lane = t & 63;
  const long row = (long)blockIdx.x * 4 + w;
  float* rp = h + row * 512;
  float4 v0 = *(float4*)(rp + lane * 4);
  float4 v1 = *(float4*)(rp + 256 + lane * 4);
  float s = ((v0.x + v0.y) + (v0.z + v0.w)) + ((v1.x + v1.y) + (v1.z + v1.w));
#pragma unroll
  for (int off = 1; off < 64; off <<= 1) s += __shfl_xor(s, off);
  float mu = s * (1.0f / 512.0f);
  float vs = (v0.x - mu) * (v0.x - mu) + (v0.y - mu) * (v0.y - mu) +
             (v0.z - mu) * (v0.z - mu) + (v0.w - mu) * (v0.w - mu) +
             (v1.x - mu) * (v1.x - mu) + (v1.y - mu) * (v1.y - mu) +
             (v1.z - mu) * (v1.z - mu) + (v1.w - mu) * (v1.w - mu);
#pragma unroll
  for (int off = 1; off < 64; off <<= 1) vs += __shfl_xor(vs, off);
  float rstd = rsqrtf(vs * (1.0f / 512.0f) + 1e-5f);
  float4 w0 = *(const float4*)(lnw + lane * 4);
  float4 w1 = *(const float4*)(lnw + 256 + lane * 4);
  float4 b0 = *(const float4*)(lnb + lane * 4);
  float4 b1 = *(const float4*)(lnb + 256 + lane * 4);
  float4 o0, o1;
  o0.x = (v0.x - mu) * rstd * w0.x + b0.x;
  o0.y = (v0.y - mu) * rstd * w0.y + b0.y;
  o0.z = (v0.z - mu) * rstd * w0.z + b0.z;
  o0.w = (v0.w - mu) * rstd * w0.w + b0.w;
  o1.x = (v1.x - mu) * rstd * w1.x + b1.x;
  o1.y = (v1.y - mu) * rstd * w1.y + b1.y;
  o1.z = (v1.z - mu) * rstd * w1.z + b1.z;
  o1.w = (v1.w - mu) * rstd * w1.w + b1.w;
  *(float4*)(rp + lane * 4) = o0;
  *(float4*)(rp + 256 + lane * 4) = o1;
}

extern "C" void kernel_launch(void* const* d_in, const int* in_sizes, int n_in,
                              void* d_out, int out_size, void* d_ws, size_t ws_size,
                              hipStream_t stream) {
  const float* x = (const float*)d_in[0];
  const float* corr = (const float*)d_in[1];
  const int* mask = (const int*)d_in[2];
  const float* w_in = (const float*)d_in[3];
  const float* b_in = (const float*)d_in[4];
  const float* w_out = (const float*)d_in[5];
  const float* b_out = (const float*)d_in[6];
  const float* ln_w = (const float*)d_in[7];
  const float* ln_b = (const float*)d_in[8];
  const float* bscale = (const float*)d_in[9];

  unsigned short* wqkv_bf = (unsigned short*)d_ws;              // 786432
  unsigned short* wout_bf = wqkv_bf + 786432;                   // 262144
  unsigned short* qkv = wout_bf + 262144;                       // 65536*1536
  unsigned short* xb_ob = qkv + (size_t)65536 * 1536;           // 65536*512 (xb then ob)

  cvt_f32_bf16<<<dim3(384), dim3(256), 0, stream>>>(w_in, wqkv_bf, 98304);
  cvt_f32_bf16<<<dim3(128), dim3(256), 0, stream>>>(w_out, wout_bf, 32768);
  cvt_f32_bf16<<<dim3(16384), dim3(256), 0, stream>>>(x, xb_ob, 4194304);

  // QKV: M=65536, N=1536 -> grid 512*12 = 6144 (divisible by 8)
  gemm_lds<0, 12><<<dim3(6144), dim3(256), 0, stream>>>(
      xb_ob, wqkv_bf, qkv, (float*)nullptr, b_in, (const float*)nullptr, 1536);

  // attn overwrites xb with ob (xb dead after QKV gemm)
  attn_kernel<<<dim3(4096), dim3(256), 0, stream>>>(qkv, corr, mask, bscale, xb_ob);

  // out-proj: M=65536, N=512 -> grid 512*4 = 2048
  gemm_lds<1, 4><<<dim3(2048), dim3(256), 0, stream>>>(
      xb_ob, wout_bf, (unsigned short*)nullptr, (float*)d_out, b_out, x, 512);

  ln_kernel<<<dim3(16384), dim3(256), 0, stream>>>((float*)d_out, ln_w, ln_b);
}

// Round 5
// 534.244 us; speedup vs baseline: 1.2696x; 1.1391x over previous
//
#include <hip/hip_runtime.h>
#include <hip/hip_bf16.h>
#include <math.h>

// Problem constants: B=512, L=128, D=512, H=8, HD=64
// M = B*L = 65536, K = D = 512, N_qkv = 3D = 1536.

typedef __attribute__((ext_vector_type(4))) float f32x4;
typedef __attribute__((ext_vector_type(8))) short bf16x8;

__device__ __forceinline__ unsigned short f2bf(float f) {
  union { float f; unsigned u; } x; x.f = f;
  return (unsigned short)((x.u + 0x7FFFu + ((x.u >> 16) & 1u)) >> 16);
}

__device__ __forceinline__ void gload16(const void* g, void* l) {
  __builtin_amdgcn_global_load_lds((const __attribute__((address_space(1))) void*)g,
                                   (__attribute__((address_space(3))) void*)l, 16, 0, 0);
}

// ---------------- f32 -> bf16 convert ----------------
__global__ void cvt_f32_bf16(const float* __restrict__ in,
                             unsigned short* __restrict__ out, int n8) {
  int i = blockIdx.x * blockDim.x + threadIdx.x;
  if (i >= n8) return;
  const float4* p = (const float4*)in + (size_t)i * 2;
  float4 a = p[0], b = p[1];
  union { bf16x8 v; short s[8]; } o;
  o.s[0] = (short)f2bf(a.x); o.s[1] = (short)f2bf(a.y);
  o.s[2] = (short)f2bf(a.z); o.s[3] = (short)f2bf(a.w);
  o.s[4] = (short)f2bf(b.x); o.s[5] = (short)f2bf(b.y);
  o.s[6] = (short)f2bf(b.z); o.s[7] = (short)f2bf(b.w);
  *(bf16x8*)(out + (size_t)i * 8) = o.v;
}

// ---------------- QKV GEMM  C = A @ Bt^T (m97 structure) ---------------------
template <int MODE, int NBX>
__global__ __launch_bounds__(256, 3) void gemm_lds(
    const unsigned short* __restrict__ A, const unsigned short* __restrict__ Bt,
    unsigned short* __restrict__ Cb, float* __restrict__ Cf,
    const float* __restrict__ bias, const float* __restrict__ resid, int ldC) {
  __shared__ __align__(16) unsigned short As[128 * 64];
  __shared__ __align__(16) unsigned short Bs[128 * 64];
  const int t = threadIdx.x;
  const int w = t >> 6, lane = t & 63;
  const int wr = w >> 1, wc = w & 1;
  const int g = lane >> 4, l16 = lane & 15;
  const int bid = blockIdx.x;
  const int cpx = (int)(gridDim.x >> 3);
  const int nid = (bid & 7) * cpx + (bid >> 3);
  const long rowBase = (long)(nid / NBX) * 128;
  const long colBase = (long)(nid % NBX) * 128;

  f32x4 acc[4][4] = {};

  for (int k0 = 0; k0 < 512; k0 += 64) {
#pragma unroll
    for (int i = 0; i < 4; ++i) {
      int flat = i * 256 + t;
      int row = flat >> 3;
      int c8 = ((flat & 7) ^ (row & 7)) << 3;
      gload16(A + (rowBase + row) * 512 + k0 + c8, (char*)As + flat * 16);
      gload16(Bt + (colBase + row) * 512 + k0 + c8, (char*)Bs + flat * 16);
    }
    __syncthreads();
#pragma unroll
    for (int kk = 0; kk < 2; ++kk) {
      bf16x8 af[4], bfr[4];
#pragma unroll
      for (int fm = 0; fm < 4; ++fm) {
        int r = wr * 64 + fm * 16 + l16;
        af[fm] = *(const bf16x8*)((char*)As + r * 128 + ((kk * 64 + g * 16) ^ ((r & 7) << 4)));
      }
#pragma unroll
      for (int fn = 0; fn < 4; ++fn) {
        int r = wc * 64 + fn * 16 + l16;
        bfr[fn] = *(const bf16x8*)((char*)Bs + r * 128 + ((kk * 64 + g * 16) ^ ((r & 7) << 4)));
      }
#pragma unroll
      for (int fm = 0; fm < 4; ++fm)
#pragma unroll
        for (int fn = 0; fn < 4; ++fn)
          acc[fm][fn] = __builtin_amdgcn_mfma_f32_16x16x32_bf16(af[fm], bfr[fn], acc[fm][fn], 0, 0, 0);
    }
    __syncthreads();
  }

#pragma unroll
  for (int fm = 0; fm < 4; ++fm) {
#pragma unroll
    for (int fn = 0; fn < 4; ++fn) {
      long col = colBase + wc * 64 + fn * 16 + l16;
      float bcol = bias[col];
#pragma unroll
      for (int r = 0; r < 4; ++r) {
        long row = rowBase + wr * 64 + fm * 16 + g * 4 + r;
        float v = acc[fm][fn][r] + bcol;
        if constexpr (MODE == 0) {
          if (col < 512) v *= 0.125f;
          Cb[row * ldC + col] = f2bf(v);
        } else {
          Cf[row * ldC + col] = v + resid[row * ldC + col];
        }
      }
    }
  }
}

// ---------------- fused out-proj + bias + residual + LayerNorm ---------------
// BM=128 rows, BN=512 (full row), BK=64; 512 thr = 8 waves, wave tile 64x128.
__global__ __launch_bounds__(512, 1) void oproj_ln(
    const unsigned short* __restrict__ Ab, const unsigned short* __restrict__ Wt,
    const float* __restrict__ x, const float* __restrict__ bout,
    const float* __restrict__ lnw, const float* __restrict__ lnb,
    float* __restrict__ out) {
  __shared__ __align__(16) unsigned short As[128 * 64];
  __shared__ __align__(16) unsigned short Bs[512 * 64];
  __shared__ float ps[128][4], pq[128][4], mus[128], rss[128];
  const int t = threadIdx.x;
  const int w = t >> 6, lane = t & 63;
  const int wr = w >> 2, wc = w & 3;
  const int g = lane >> 4, l16 = lane & 15;
  const long rowBase = (long)blockIdx.x * 128;

  f32x4 acc[4][8] = {};

  for (int k0 = 0; k0 < 512; k0 += 64) {
#pragma unroll
    for (int i = 0; i < 2; ++i) {
      int flat = i * 512 + t;
      int row = flat >> 3;
      int c8 = ((flat & 7) ^ (row & 7)) << 3;
      gload16(Ab + (rowBase + row) * 512 + k0 + c8, (char*)As + flat * 16);
    }
#pragma unroll
    for (int i = 0; i < 8; ++i) {
      int flat = i * 512 + t;
      int row = flat >> 3;
      int c8 = ((flat & 7) ^ (row & 7)) << 3;
      gload16(Wt + row * 512 + k0 + c8, (char*)Bs + flat * 16);
    }
    __syncthreads();
#pragma unroll
    for (int kk = 0; kk < 2; ++kk) {
      bf16x8 af[4], bfr[8];
#pragma unroll
      for (int fm = 0; fm < 4; ++fm) {
        int r = wr * 64 + fm * 16 + l16;
        af[fm] = *(const bf16x8*)((char*)As + r * 128 + ((kk * 64 + g * 16) ^ ((r & 7) << 4)));
      }
#pragma unroll
      for (int fn = 0; fn < 8; ++fn) {
        int n = wc * 128 + fn * 16 + l16;
        bfr[fn] = *(const bf16x8*)((char*)Bs + n * 128 + ((kk * 64 + g * 16) ^ ((n & 7) << 4)));
      }
#pragma unroll
      for (int fm = 0; fm < 4; ++fm)
#pragma unroll
        for (int fn = 0; fn < 8; ++fn)
          acc[fm][fn] = __builtin_amdgcn_mfma_f32_16x16x32_bf16(af[fm], bfr[fn], acc[fm][fn], 0, 0, 0);
    }
    __syncthreads();
  }

  // h = acc + bias + resid; per-row partial sums into LDS
  float bo[8];
#pragma unroll
  for (int fn = 0; fn < 8; ++fn) bo[fn] = bout[wc * 128 + fn * 16 + l16];

#pragma unroll
  for (int fm = 0; fm < 4; ++fm) {
#pragma unroll
    for (int r = 0; r < 4; ++r) {
      const int rloc = wr * 64 + fm * 16 + g * 4 + r;
      const long row = rowBase + rloc;
      float sh = 0.f, sq = 0.f;
#pragma unroll
      for (int fn = 0; fn < 8; ++fn) {
        int col = wc * 128 + fn * 16 + l16;
        float h = acc[fm][fn][r] + bo[fn] + x[row * 512 + col];
        acc[fm][fn][r] = h;
        sh += h;
        sq += h * h;
      }
#pragma unroll
      for (int off = 1; off < 16; off <<= 1) {
        sh += __shfl_xor(sh, off);
        sq += __shfl_xor(sq, off);
      }
      if (l16 == 0) {
        ps[rloc][wc] = sh;
        pq[rloc][wc] = sq;
      }
    }
  }
  __syncthreads();
  if (t < 128) {
    float s = ps[t][0] + ps[t][1] + ps[t][2] + ps[t][3];
    float q = pq[t][0] + pq[t][1] + pq[t][2] + pq[t][3];
    float mu = s * (1.0f / 512.0f);
    float var = q * (1.0f / 512.0f) - mu * mu;
    mus[t] = mu;
    rss[t] = rsqrtf(var + 1e-5f);
  }
  __syncthreads();

  float lw[8], lb[8];
#pragma unroll
  for (int fn = 0; fn < 8; ++fn) {
    lw[fn] = lnw[wc * 128 + fn * 16 + l16];
    lb[fn] = lnb[wc * 128 + fn * 16 + l16];
  }
#pragma unroll
  for (int fm = 0; fm < 4; ++fm) {
#pragma unroll
    for (int r = 0; r < 4; ++r) {
      const int rloc = wr * 64 + fm * 16 + g * 4 + r;
      const long row = rowBase + rloc;
      const float mu = mus[rloc], rs = rss[rloc];
#pragma unroll
      for (int fn = 0; fn < 8; ++fn) {
        int col = wc * 128 + fn * 16 + l16;
        out[row * 512 + col] = (acc[fm][fn][r] - mu) * rs * lw[fn] + lb[fn];
      }
    }
  }
}

// ---------------- attention per (b, h) ----------------
// K staged in swizzled LDS (shared by all 4 waves); q direct-to-reg;
// V^T + P via LDS with stride 136 (s-dim rows are 128 long + 8 pad).
__global__ __launch_bounds__(256, 2) void attn_kernel(
    const unsigned short* __restrict__ qkv, const float* __restrict__ corr,
    const int* __restrict__ mask, const float* __restrict__ bias_scale,
    unsigned short* __restrict__ o) {
  __shared__ __align__(16) unsigned short kt[128 * 64];
  __shared__ __align__(16) unsigned short Pl[4][32 * 136];
  __shared__ __align__(16) unsigned short vt[64 * 136];
  __shared__ float biasl[128];
  const int t = threadIdx.x;
  const int w = t >> 6, lane = t & 63;
  const int g = lane >> 4, l16 = lane & 15;
  const int b = blockIdx.x >> 3, h = blockIdx.x & 7;
  const long qkvBase = (long)b * 128 * 1536;

  // K -> LDS (swizzled source, linear dest)
#pragma unroll
  for (int i = 0; i < 4; ++i) {
    int flat = i * 256 + t;
    int row = flat >> 3;
    int c8 = ((flat & 7) ^ (row & 7)) << 3;
    gload16(qkv + qkvBase + (long)row * 1536 + 512 + h * 64 + c8, (char*)kt + flat * 16);
  }

  // stage V^T : vt[d][s] = v[s][d]
#pragma unroll
  for (int i = 0; i < 4; ++i) {
    int q = t + i * 256;
    int row = q >> 3, c8 = q & 7;
    union { bf16x8 v; unsigned short s[8]; } u;
    u.v = *(const bf16x8*)(qkv + qkvBase + (long)row * 1536 + 1024 + h * 64 + c8 * 8);
#pragma unroll
    for (int j = 0; j < 8; ++j) vt[(c8 * 8 + j) * 136 + row] = u.s[j];
  }
  if (t < 128) {
    float bs = bias_scale[0];
    biasl[t] = mask[b * 128 + t] ? -INFINITY : bs * corr[b * 128 + t];
  }

  // q fragments direct from global
  bf16x8 aq[2][2];
#pragma unroll
  for (int fm = 0; fm < 2; ++fm)
#pragma unroll
    for (int kk = 0; kk < 2; ++kk)
      aq[fm][kk] = *(const bf16x8*)(qkv + qkvBase + (long)(w * 32 + fm * 16 + l16) * 1536 + h * 64 + kk * 32 + g * 8);

  __syncthreads();  // kt (DMA), vt, biasl ready

  // S = q @ k^T ; k from swizzled LDS
  f32x4 accS[2][8] = {};
#pragma unroll
  for (int fn = 0; fn < 8; ++fn) {
    int r = fn * 16 + l16;
    bf16x8 bk0 = *(const bf16x8*)((char*)kt + r * 128 + ((g * 16) ^ ((r & 7) << 4)));
    bf16x8 bk1 = *(const bf16x8*)((char*)kt + r * 128 + ((64 + g * 16) ^ ((r & 7) << 4)));
#pragma unroll
    for (int fm = 0; fm < 2; ++fm) {
      accS[fm][fn] = __builtin_amdgcn_mfma_f32_16x16x32_bf16(aq[fm][0], bk0, accS[fm][fn], 0, 0, 0);
      accS[fm][fn] = __builtin_amdgcn_mfma_f32_16x16x32_bf16(aq[fm][1], bk1, accS[fm][fn], 0, 0, 0);
    }
  }

  float bv[8];
#pragma unroll
  for (int fn = 0; fn < 8; ++fn) bv[fn] = biasl[fn * 16 + l16];

  float rinv[2][4];
#pragma unroll
  for (int fm = 0; fm < 2; ++fm) {
#pragma unroll
    for (int r = 0; r < 4; ++r) {
      float m = -INFINITY;
#pragma unroll
      for (int fn = 0; fn < 8; ++fn) m = fmaxf(m, accS[fm][fn][r] + bv[fn]);
#pragma unroll
      for (int off = 1; off < 16; off <<= 1) m = fmaxf(m, __shfl_xor(m, off));
      float s = 0.f;
#pragma unroll
      for (int fn = 0; fn < 8; ++fn) {
        float p = __expf(accS[fm][fn][r] + bv[fn] - m);
        accS[fm][fn][r] = p;
        s += p;
      }
#pragma unroll
      for (int off = 1; off < 16; off <<= 1) s += __shfl_xor(s, off);
      rinv[fm][r] = 1.0f / s;
#pragma unroll
      for (int fn = 0; fn < 8; ++fn)
        Pl[w][(fm * 16 + g * 4 + r) * 136 + fn * 16 + l16] = f2bf(accS[fm][fn][r]);
    }
  }

  // O = P @ V (wave-private P; within-wave LDS ordering)
  f32x4 accO[2][4] = {};
#pragma unroll
  for (int kk = 0; kk < 4; ++kk) {
    bf16x8 ap[2], bw[4];
#pragma unroll
    for (int fm = 0; fm < 2; ++fm)
      ap[fm] = *(const bf16x8*)&Pl[w][(fm * 16 + l16) * 136 + kk * 32 + g * 8];
#pragma unroll
    for (int fn = 0; fn < 4; ++fn)
      bw[fn] = *(const bf16x8*)&vt[(fn * 16 + l16) * 136 + kk * 32 + g * 8];
#pragma unroll
    for (int fm = 0; fm < 2; ++fm)
#pragma unroll
      for (int fn = 0; fn < 4; ++fn)
        accO[fm][fn] = __builtin_amdgcn_mfma_f32_16x16x32_bf16(ap[fm], bw[fn], accO[fm][fn], 0, 0, 0);
  }

  const long oBase = (long)b * 128 * 512 + (long)h * 64;
#pragma unroll
  for (int fm = 0; fm < 2; ++fm)
#pragma unroll
    for (int fn = 0; fn < 4; ++fn)
#pragma unroll
      for (int r = 0; r < 4; ++r)
        o[oBase + (long)(w * 32 + fm * 16 + g * 4 + r) * 512 + fn * 16 + l16] =
            f2bf(accO[fm][fn][r] * rinv[fm][r]);
}

extern "C" void kernel_launch(void* const* d_in, const int* in_sizes, int n_in,
                              void* d_out, int out_size, void* d_ws, size_t ws_size,
                              hipStream_t stream) {
  const float* x = (const float*)d_in[0];
  const float* corr = (const float*)d_in[1];
  const int* mask = (const int*)d_in[2];
  const float* w_in = (const float*)d_in[3];
  const float* b_in = (const float*)d_in[4];
  const float* w_out = (const float*)d_in[5];
  const float* b_out = (const float*)d_in[6];
  const float* ln_w = (const float*)d_in[7];
  const float* ln_b = (const float*)d_in[8];
  const float* bscale = (const float*)d_in[9];

  unsigned short* wqkv_bf = (unsigned short*)d_ws;              // 786432
  unsigned short* wout_bf = wqkv_bf + 786432;                   // 262144
  unsigned short* qkv = wout_bf + 262144;                       // 65536*1536
  unsigned short* xb_ob = qkv + (size_t)65536 * 1536;           // 65536*512 (xb then ob)

  cvt_f32_bf16<<<dim3(384), dim3(256), 0, stream>>>(w_in, wqkv_bf, 98304);
  cvt_f32_bf16<<<dim3(128), dim3(256), 0, stream>>>(w_out, wout_bf, 32768);
  cvt_f32_bf16<<<dim3(16384), dim3(256), 0, stream>>>(x, xb_ob, 4194304);

  gemm_lds<0, 12><<<dim3(6144), dim3(256), 0, stream>>>(
      xb_ob, wqkv_bf, qkv, (float*)nullptr, b_in, (const float*)nullptr, 1536);

  attn_kernel<<<dim3(4096), dim3(256), 0, stream>>>(qkv, corr, mask, bscale, xb_ob);

  oproj_ln<<<dim3(512), dim3(512), 0, stream>>>(
      xb_ob, wout_bf, x, b_out, ln_w, ln_b, (float*)d_out);
}